// Round 1
// baseline (220.499 us; speedup 1.0000x reference)
//
#include <hip/hip_runtime.h>
#include <hip/hip_bf16.h>
#include <math.h>

// Problem shape (fixed): x [B,T,D] fp32, log_alpha scalar fp32, out [B,T,D] fp32.
#define B_ 4
#define T_ 4096
#define D_ 512
#define BT 128                 // t/s tile size per block (128x128 pair)
#define BK 64                  // K elems per pipeline step (fp8: 64 B/row)
#define STEPS (D_ / BK)        // 8
#define NT (T_ / BT)           // 32 tiles per batch
#define NPAIR (NT * (NT + 1) / 2)  // 528 lower-triangle tile pairs
#define NBLK (NPAIR * B_)      // 2112 = 8 XCDs * 264
#define SCL 0x7F7F7F7F         // e8m0 unit scale (127 -> 2^0) in every byte

// Workspace layout:
//   [0 .. 64KiB)                maxsim as order-preserving uint32 [B*T]
//   [64KiB .. 64KiB+B*T*D)      xn: normalized rows, fp8 e4m3, PLAIN layout
//     (chunk C of each 64-B K-slab = elems [16C,16C+16)). The 32x32x64
//     scaled-MFMA fragment (32 B/lane = one K-half) reads chunk pairs
//     {2h, 2h+1}, so no unit-interleave is needed anymore.

typedef float f32x16 __attribute__((ext_vector_type(16)));
typedef int v4i __attribute__((ext_vector_type(4)));
typedef int v8i __attribute__((ext_vector_type(8)));

// monotone float -> uint so unsigned atomicMax orders like float
__device__ __forceinline__ unsigned f2ord(float f) {
    unsigned u = __float_as_uint(f);
    return (u & 0x80000000u) ? ~u : (u | 0x80000000u);
}
__device__ __forceinline__ float ord2f(unsigned u) {
    unsigned b = (u & 0x80000000u) ? (u ^ 0x80000000u) : ~u;
    return __uint_as_float(b);
}

__device__ __forceinline__ void async16(const unsigned char* g, unsigned char* l) {
    // 16B/lane global->LDS DMA; LDS dest = wave-uniform base + lane*16
    __builtin_amdgcn_global_load_lds(
        (const __attribute__((address_space(1))) unsigned int*)g,
        (__attribute__((address_space(3))) unsigned int*)l, 16, 0, 0);
}

// ---- Kernel 1: one wave per row. inv-norm + plain fp8 write + init ----
__global__ __launch_bounds__(256) void k_norm(const float* __restrict__ x,
                                              unsigned char* __restrict__ xn,
                                              unsigned* __restrict__ maxsim) {
    int w = (blockIdx.x * 256 + threadIdx.x) >> 6;   // row id (B*T rows)
    int l = threadIdx.x & 63;
    const float4* xr = (const float4*)(x + (size_t)w * D_);
    float4 a = xr[l];             // elems 4l..4l+3
    float4 b = xr[l + 64];        // elems 256+4l..
    float ss = a.x * a.x + a.y * a.y + a.z * a.z + a.w * a.w +
               b.x * b.x + b.y * b.y + b.z * b.z + b.w * b.w;
#pragma unroll
    for (int off = 32; off > 0; off >>= 1) ss += __shfl_xor(ss, off);
    float inv = 1.0f / fmaxf(sqrtf(ss), 1e-12f);
    int u0 = __builtin_amdgcn_cvt_pk_fp8_f32(a.x * inv, a.y * inv, 0, false);
    u0 = __builtin_amdgcn_cvt_pk_fp8_f32(a.z * inv, a.w * inv, u0, true);
    int u1 = __builtin_amdgcn_cvt_pk_fp8_f32(b.x * inv, b.y * inv, 0, false);
    u1 = __builtin_amdgcn_cvt_pk_fp8_f32(b.z * inv, b.w * inv, u1, true);
    // plain layout: uint index l = bytes 4l..4l+3 = elems 4l..4l+3
    unsigned* xo = (unsigned*)(xn + (size_t)w * D_);
    xo[l]      = (unsigned)u0;
    xo[l + 64] = (unsigned)u1;
    if (l == 0) maxsim[w] = f2ord(-2.0f);
}

// ---- Kernel 2: one block per (ti,si) pair; SCALED fp8 MFMA 32x32x64 ----
// Same verified R6 schedule: 3-stage circular DMA buffer, ONE raw s_barrier
// per K-step, counted vmcnt(4). BK=64 fp8: 16 KB/stage, 8 steps.
// Change vs prior round: mfma_f32_16x16x32_fp8 (2.19 PF ceiling) ->
// mfma_scale_f32_32x32x64_f8f6f4 with unit e8m0 scales (4.69 PF ceiling,
// m59): 4 MFMA/step/wave instead of 32, same LDS bytes. Chunk-XOR swizzle
// p = g ^ ((r>>1)&3) kept; the 32-row b128 read pattern has the same
// 2-lanes-per-bank-group profile per 16-lane quarter (conflict-free).
// XCD-chunked remap (T1): 2112 blocks = 8 x 264; each XCD owns one batch's
// contiguous pair range -> ~2.6 MB L2 working set < 4 MiB.
// History: (256,4) spilled (R2); bf16-BK=64 killed occupancy (R3); global-
// direct frags TA-bound (R5); 1-wave blocks no TLP (R7); 256x128 tile lost
// to occupancy+tail (R8); b64 frag reads 4-way conflicted (R9).
__global__ __launch_bounds__(256) void k_maxsim(const unsigned char* __restrict__ xn,
                                                unsigned* __restrict__ maxsim) {
    __shared__ __align__(16) unsigned char Buf[3][16384];
    // XCD-chunked bijective remap (gridDim.x = 528 ≡ 0 mod 8, so linear id
    // mod 8 tracks blockIdx.x mod 8 across y).
    const int lin = blockIdx.x + NPAIR * blockIdx.y;
    const int wrk = (lin & 7) * (NBLK / 8) + (lin >> 3);
    const int b = wrk / NPAIR;
    const int p = wrk - b * NPAIR;
    // triangular decode p -> (ti, si), si <= ti
    int ti = (int)((sqrtf(8.0f * (float)p + 1.0f) - 1.0f) * 0.5f);
    while ((ti + 1) * (ti + 2) / 2 <= p) ti++;
    while (ti * (ti + 1) / 2 > p) ti--;
    const int si = p - ti * (ti + 1) / 2;
    const int t0 = ti * BT, s0 = si * BT;

    const int tid = threadIdx.x;
    const int wave = tid >> 6, lane = tid & 63;
    const int wm = wave >> 1, wn = wave & 1;     // 2x2 waves -> 64x64 each
    const int lr = lane & 31;                    // row within 32-row frag
    const int h  = lane >> 5;                    // K-half (chunks 2h,2h+1)

    const unsigned char* Ab = xn + (size_t)(b * T_ + t0) * D_;
    const unsigned char* Bb = xn + (size_t)(b * T_ + s0) * D_;

    // DMA addressing: chunk index c -> row r = c>>2 (4x16B chunks = 64 B/row),
    // position c&3 holds global chunk g = (c&3) ^ ((r>>1)&3).
    const int c0 = tid,       r0_ = c0 >> 2, g0 = (c0 & 3) ^ ((r0_ >> 1) & 3);
    const int c1 = 256 + tid, r1_ = c1 >> 2, g1 = (c1 & 3) ^ ((r1_ >> 1) & 3);
    const unsigned char* gA0 = Ab + (size_t)r0_ * D_ + g0 * 16;
    const unsigned char* gA1 = Ab + (size_t)r1_ * D_ + g1 * 16;
    const unsigned char* gB0 = Bb + (size_t)r0_ * D_ + g0 * 16;
    const unsigned char* gB1 = Bb + (size_t)r1_ * D_ + g1 * 16;
    const int ldsb0 = (wave * 64) * 16;          // wave-uniform chunk base (bytes)
    const int ldsb1 = (256 + wave * 64) * 16;

#define STAGE(step, st)                                            \
    do {                                                           \
        async16(gA0 + (step) * BK, &Buf[st][ldsb0]);               \
        async16(gB0 + (step) * BK, &Buf[st][8192 + ldsb0]);        \
        async16(gA1 + (step) * BK, &Buf[st][ldsb1]);               \
        async16(gB1 + (step) * BK, &Buf[st][8192 + ldsb1]);        \
    } while (0)

#define MFMA(Aop, Bop, C) \
    __builtin_amdgcn_mfma_scale_f32_32x32x64_f8f6f4((Aop), (Bop), (C), 0, 0, 0, SCL, 0, SCL)

    f32x16 acc[2][2];
#pragma unroll
    for (int i = 0; i < 2; i++)
#pragma unroll
        for (int j = 0; j < 2; j++)
#pragma unroll
            for (int r = 0; r < 16; r++) acc[i][j][r] = 0.0f;

    // Fragment read offsets. Row r = (frag_base + lr); s = (r>>1)&3 is
    // independent of frag_base (multiples of 32). First chunk at position
    // (2h)^s, second at ((2h)^s)^1 -> addr XOR 16.
    const int s_ = (lr >> 1) & 3;
    const int pb = ((2 * h) ^ s_) * 16;
    const int offA = (wm * 64 + lr) * 64 + pb;          // A frag i at +i*2048
    const int offB = 8192 + (wn * 64 + lr) * 64 + pb;   // B frag j at +j*2048

    // prologue: steps 0 and 1 in flight (4 DMA instrs each per wave)
    STAGE(0, 0);
    STAGE(1, 1);

#pragma unroll
    for (int k = 0; k < STEPS; ++k) {
        const int cur = k % 3;
        // simm16: vmcnt lo[3:0] | expcnt(7)<<4 | lgkmcnt(15)<<8
        if (k == STEPS - 1) __builtin_amdgcn_s_waitcnt(0x0F70);  // vmcnt(0)
        else                __builtin_amdgcn_s_waitcnt(0x0F74);  // vmcnt(4)
        __builtin_amdgcn_s_barrier();
        __asm__ __volatile__("" ::: "memory");   // pin LDS reads below barrier
        if (k + 2 < STEPS) STAGE(k + 2, (k + 2) % 3);

        const unsigned char* Bs = &Buf[cur][0];
        v4i a0l = *(const v4i*)(Bs + offA);
        v4i a0h = *(const v4i*)(Bs + (offA ^ 16));
        v4i a1l = *(const v4i*)(Bs + offA + 2048);
        v4i a1h = *(const v4i*)(Bs + (offA ^ 16) + 2048);
        v4i b0l = *(const v4i*)(Bs + offB);
        v4i b0h = *(const v4i*)(Bs + (offB ^ 16));
        v4i b1l = *(const v4i*)(Bs + offB + 2048);
        v4i b1h = *(const v4i*)(Bs + (offB ^ 16) + 2048);
        const v8i A0 = __builtin_shufflevector(a0l, a0h, 0, 1, 2, 3, 4, 5, 6, 7);
        const v8i A1 = __builtin_shufflevector(a1l, a1h, 0, 1, 2, 3, 4, 5, 6, 7);
        const v8i B0 = __builtin_shufflevector(b0l, b0h, 0, 1, 2, 3, 4, 5, 6, 7);
        const v8i B1 = __builtin_shufflevector(b1l, b1h, 0, 1, 2, 3, 4, 5, 6, 7);
        acc[0][0] = MFMA(A0, B0, acc[0][0]);
        acc[0][1] = MFMA(A0, B1, acc[0][1]);
        acc[1][0] = MFMA(A1, B0, acc[1][0]);
        acc[1][1] = MFMA(A1, B1, acc[1][1]);
    }
#undef STAGE
#undef MFMA

    // epilogue: per-row max over this tile's s-columns, then global atomicMax.
    // 32x32 C/D layout (verified, shape-determined): col = lane&31,
    // row = (reg&3) + 8*(reg>>2) + 4*(lane>>5).
    const bool diag = (ti == si);
#pragma unroll
    for (int i = 0; i < 2; i++) {
#pragma unroll
        for (int reg = 0; reg < 16; reg++) {
            const int tl = wm * 64 + i * 32 + (reg & 3) + 8 * (reg >> 2) + 4 * h;
            float m = -2.0f;
            {
                const int sl0 = wn * 64 + lr;          // j = 0
                float v0 = acc[i][0][reg];
                if (!diag || sl0 < tl) m = fmaxf(m, v0);
                const int sl1 = sl0 + 32;              // j = 1
                float v1 = acc[i][1][reg];
                if (!diag || sl1 < tl) m = fmaxf(m, v1);
            }
#pragma unroll
            for (int off = 1; off < 32; off <<= 1) m = fmaxf(m, __shfl_xor(m, off));
            if (lr == 0) atomicMax(&maxsim[b * T_ + t0 + tl], f2ord(m));
        }
    }
}

// ---- Kernel 3: gate + tanh-GELU, one float4 per thread ----
__device__ __forceinline__ float gelu_tanh(float y) {
    float t = tanhf(0.7978845608028654f * (y + 0.044715f * y * y * y));
    return 0.5f * y * (1.0f + t);
}

__global__ __launch_bounds__(256) void k_gate(const float* __restrict__ x,
                                              const float* __restrict__ log_alpha,
                                              const unsigned* __restrict__ maxsim,
                                              float* __restrict__ out) {
    int idx = blockIdx.x * 256 + threadIdx.x;     // one float4 per thread
    float la = log_alpha[0];
    float alpha = (la > 20.0f) ? la : log1pf(expf(la));
    int row = idx >> 7;                           // 128 float4-threads per row
    float m = fmaxf(ord2f(maxsim[row]), -1.0f);
    float novelty = 1.0f - (m + 1.0f) * 0.5f;
    float gate = 1.0f + alpha * novelty;
    float4 v = ((const float4*)x)[idx];
    float4 o;
    o.x = gelu_tanh(v.x * gate);
    o.y = gelu_tanh(v.y * gate);
    o.z = gelu_tanh(v.z * gate);
    o.w = gelu_tanh(v.w * gate);
    ((float4*)out)[idx] = o;
}

extern "C" void kernel_launch(void* const* d_in, const int* in_sizes, int n_in,
                              void* d_out, int out_size, void* d_ws, size_t ws_size,
                              hipStream_t stream) {
    const float* x = (const float*)d_in[0];
    const float* log_alpha = (const float*)d_in[1];
    float* out = (float*)d_out;

    unsigned* maxsim = (unsigned*)d_ws;
    unsigned char* xn = (unsigned char*)d_ws + 65536;

    const int rows = B_ * T_;                     // 16384
    k_norm<<<rows / 4, 256, 0, stream>>>(x, xn, maxsim);

    dim3 g2(NPAIR, B_);
    k_maxsim<<<g2, 256, 0, stream>>>(xn, maxsim);

    k_gate<<<(B_ * T_ * D_ / 4) / 256, 256, 0, stream>>>(x, log_alpha, maxsim, out);
}

// Round 2
// 140.098 us; speedup vs baseline: 1.5739x; 1.5739x over previous
//
#include <hip/hip_runtime.h>
#include <hip/hip_bf16.h>
#include <math.h>

// Problem shape (fixed): x [B,T,D] fp32, log_alpha scalar fp32, out [B,T,D] fp32.
#define B_ 4
#define T_ 4096
#define D_ 512
#define BT 128                 // t/s tile size per block (128x128 pair)
#define BK 64                  // K elems per pipeline step (fp8: 64 B/row)
#define STEPS (D_ / BK)        // 8
#define NT (T_ / BT)           // 32 tiles per batch
#define NPAIR (NT * (NT + 1) / 2)  // 528 lower-triangle tile pairs
#define NBLK (NPAIR * B_)      // 2112 = 8 XCDs * 264

// Workspace layout:
//   [0 .. 64KiB)                maxsim as order-preserving uint32 [B*T]
//   [64KiB .. 64KiB+B*T*D)      xn: normalized rows, fp8 e4m3, UNIT-INTERLEAVED:
//     within each 64-elem K-slab, 16B chunk C holds logical 8B units
//     {elems C*8..C*8+7} (h=0) then {elems 32+C*8..+7} (h=1). This makes one
//     ds_read_b128 serve both MFMA k-halves of a row -> R2's verified
//     zero-conflict LDS read pattern (vs R9's 4-way-conflicted b64 reads).

typedef float f32x4 __attribute__((ext_vector_type(4)));
typedef long i64x2 __attribute__((ext_vector_type(2)));

// monotone float -> uint so unsigned atomicMax orders like float
__device__ __forceinline__ unsigned f2ord(float f) {
    unsigned u = __float_as_uint(f);
    return (u & 0x80000000u) ? ~u : (u | 0x80000000u);
}
__device__ __forceinline__ float ord2f(unsigned u) {
    unsigned b = (u & 0x80000000u) ? (u ^ 0x80000000u) : ~u;
    return __uint_as_float(b);
}

__device__ __forceinline__ void async16(const unsigned char* g, unsigned char* l) {
    // 16B/lane global->LDS DMA; LDS dest = wave-uniform base + lane*16
    __builtin_amdgcn_global_load_lds(
        (const __attribute__((address_space(1))) unsigned int*)g,
        (__attribute__((address_space(3))) unsigned int*)l, 16, 0, 0);
}

// ---- Kernel 1: one wave per row. inv-norm + permuted fp8 write + init ----
__global__ __launch_bounds__(256) void k_norm(const float* __restrict__ x,
                                              unsigned char* __restrict__ xn,
                                              unsigned* __restrict__ maxsim) {
    int w = (blockIdx.x * 256 + threadIdx.x) >> 6;   // row id (B*T rows)
    int l = threadIdx.x & 63;
    const float4* xr = (const float4*)(x + (size_t)w * D_);
    float4 a = xr[l];             // elems 4l..4l+3
    float4 b = xr[l + 64];        // elems 256+4l..
    float ss = a.x * a.x + a.y * a.y + a.z * a.z + a.w * a.w +
               b.x * b.x + b.y * b.y + b.z * b.z + b.w * b.w;
#pragma unroll
    for (int off = 32; off > 0; off >>= 1) ss += __shfl_xor(ss, off);
    float inv = 1.0f / fmaxf(sqrtf(ss), 1e-12f);
    int u0 = __builtin_amdgcn_cvt_pk_fp8_f32(a.x * inv, a.y * inv, 0, false);
    u0 = __builtin_amdgcn_cvt_pk_fp8_f32(a.z * inv, a.w * inv, u0, true);
    int u1 = __builtin_amdgcn_cvt_pk_fp8_f32(b.x * inv, b.y * inv, 0, false);
    u1 = __builtin_amdgcn_cvt_pk_fp8_f32(b.z * inv, b.w * inv, u1, true);
    // permuted address (in uints) for elem group e0=4l:
    //   slab (l>>4)*16 | chunk ((l>>1)&3)*4 | half ((l>>3)&1)*2 | (l&1)
    unsigned* xo = (unsigned*)(xn + (size_t)w * D_);
    int off4 = (l >> 4) * 16 + ((l >> 1) & 3) * 4 + ((l >> 3) & 1) * 2 + (l & 1);
    xo[off4]      = (unsigned)u0;   // elems 4l..4l+3
    xo[off4 + 64] = (unsigned)u1;   // elems 256+4l.. (+4 slabs = +256 B)
    if (l == 0) maxsim[w] = f2ord(-2.0f);
}

// ---- Kernel 2: one block per (ti,si) pair; fp8 MFMA; R6 3-stage pipeline ----
// 3-stage circular DMA buffer, ONE raw s_barrier per K-step, in-loop wait
// vmcnt(4). BK=64 fp8: 16 KB/stage (same as R6 bf16), 8 steps, 32 MFMA/step.
// LDS per stage: A[128 rows][64 B] then B at +8192. Chunk-XOR swizzle
// (R2-verified ZERO conflicts): 16B chunk at position P of row r holds
// global chunk P ^ ((r>>1)&3); reader b128 at position qa^((la>>1)&3) gets
// both k-half fragments (unit-interleaved xn layout).
// R11 delta (ONLY change vs the verified 131us kernel): XCD-chunked block
// remap (T1). 2112 blocks = 8 XCDs x 264; linear dispatch id mod 8 tracks
// the XCD, so each XCD owns 264 consecutive (b,p) pairs -> A/B panel
// working set ~2.8 MB fits one XCD's 4 MiB L2 (vs all XCDs streaming all
// of xn). Bijective since NBLK % 8 == 0.
// History: (256,4) spilled (R2); bf16-BK=64 killed occupancy (R3); global-
// direct frags TA-bound (R5); 1-wave blocks no TLP (R7); 256x128 tile lost
// to occupancy+tail (R8); b64 frag reads 4-way conflicted (R9); scaled
// 32x32x64 MFMA restructure -> latency-exposed, 3.5x regression (R10).
__global__ __launch_bounds__(256) void k_maxsim(const unsigned char* __restrict__ xn,
                                                unsigned* __restrict__ maxsim) {
    __shared__ __align__(16) unsigned char Buf[3][16384];
    // XCD-chunked bijective remap (gridDim.x = 528 ≡ 0 mod 8, so linear id
    // mod 8 tracks blockIdx.x mod 8 across y).
    const int lin = blockIdx.x + NPAIR * blockIdx.y;
    const int wrk = (lin & 7) * (NBLK / 8) + (lin >> 3);
    const int b = wrk / NPAIR;
    const int p = wrk - b * NPAIR;
    // triangular decode p -> (ti, si), si <= ti
    int ti = (int)((sqrtf(8.0f * (float)p + 1.0f) - 1.0f) * 0.5f);
    while ((ti + 1) * (ti + 2) / 2 <= p) ti++;
    while (ti * (ti + 1) / 2 > p) ti--;
    const int si = p - ti * (ti + 1) / 2;
    const int t0 = ti * BT, s0 = si * BT;

    const int tid = threadIdx.x;
    const int wave = tid >> 6, lane = tid & 63;
    const int wm = wave >> 1, wn = wave & 1;     // 2x2 waves -> 64x64 each
    const int qa = lane >> 4, la = lane & 15;
    const int swz = (la >> 1) & 3;               // read-side row-phase XOR

    const unsigned char* Ab = xn + (size_t)(b * T_ + t0) * D_;
    const unsigned char* Bb = xn + (size_t)(b * T_ + s0) * D_;

    // DMA addressing: chunk index c -> row r = c>>2 (4x16B chunks = 64 B/row),
    // position c&3 holds global chunk g = (c&3) ^ ((r>>1)&3).
    const int c0 = tid,       r0_ = c0 >> 2, g0 = (c0 & 3) ^ ((r0_ >> 1) & 3);
    const int c1 = 256 + tid, r1_ = c1 >> 2, g1 = (c1 & 3) ^ ((r1_ >> 1) & 3);
    const unsigned char* gA0 = Ab + (size_t)r0_ * D_ + g0 * 16;
    const unsigned char* gA1 = Ab + (size_t)r1_ * D_ + g1 * 16;
    const unsigned char* gB0 = Bb + (size_t)r0_ * D_ + g0 * 16;
    const unsigned char* gB1 = Bb + (size_t)r1_ * D_ + g1 * 16;
    const int ldsb0 = (wave * 64) * 16;          // wave-uniform chunk base (bytes)
    const int ldsb1 = (256 + wave * 64) * 16;

#define STAGE(step, st)                                            \
    do {                                                           \
        async16(gA0 + (step) * BK, &Buf[st][ldsb0]);               \
        async16(gB0 + (step) * BK, &Buf[st][8192 + ldsb0]);        \
        async16(gA1 + (step) * BK, &Buf[st][ldsb1]);               \
        async16(gB1 + (step) * BK, &Buf[st][8192 + ldsb1]);        \
    } while (0)

    f32x4 acc[4][4];
#pragma unroll
    for (int i = 0; i < 4; i++)
#pragma unroll
        for (int j = 0; j < 4; j++) acc[i][j] = (f32x4){0.f, 0.f, 0.f, 0.f};

    const int rpos = (qa ^ swz) * 16;            // b128 position within 64-B row

    // prologue: steps 0 and 1 in flight (4 DMA instrs each per wave)
    STAGE(0, 0);
    STAGE(1, 1);

#pragma unroll
    for (int k = 0; k < STEPS; ++k) {
        const int cur = k % 3;
        // simm16: vmcnt lo[3:0] | expcnt(7)<<4 | lgkmcnt(15)<<8
        if (k == STEPS - 1) __builtin_amdgcn_s_waitcnt(0x0F70);  // vmcnt(0)
        else                __builtin_amdgcn_s_waitcnt(0x0F74);  // vmcnt(4)
        __builtin_amdgcn_s_barrier();
        __asm__ __volatile__("" ::: "memory");   // pin LDS reads below barrier
        if (k + 2 < STEPS) STAGE(k + 2, (k + 2) % 3);

        const unsigned char* As = &Buf[cur][0];
        const unsigned char* Bs = &Buf[cur][8192];
        // ONE b128 per row: [0]=h0 fragment (k 0..31), [1]=h1 (k 32..63)
        i64x2 af[4], bfr[4];
#pragma unroll
        for (int i = 0; i < 4; i++)
            af[i] = *(const i64x2*)&As[(wm * 64 + i * 16 + la) * 64 + rpos];
#pragma unroll
        for (int j = 0; j < 4; j++)
            bfr[j] = *(const i64x2*)&Bs[(wn * 64 + j * 16 + la) * 64 + rpos];
#pragma unroll
        for (int h = 0; h < 2; h++)
#pragma unroll
            for (int i = 0; i < 4; i++)
#pragma unroll
                for (int j = 0; j < 4; j++)
                    acc[i][j] = __builtin_amdgcn_mfma_f32_16x16x32_fp8_fp8(
                        af[i][h], bfr[j][h], acc[i][j], 0, 0, 0);
    }
#undef STAGE

    // epilogue: per-row max over this tile's s-columns, then global atomicMax.
    // C/D layout (verified, dtype-independent): col = lane&15, row = (lane>>4)*4+reg
    const bool diag = (ti == si);
#pragma unroll
    for (int i = 0; i < 4; i++) {
#pragma unroll
        for (int r = 0; r < 4; r++) {
            int tl = wm * 64 + i * 16 + qa * 4 + r;   // local t row
            float m = -2.0f;
#pragma unroll
            for (int j = 0; j < 4; j++) {
                int sl = wn * 64 + j * 16 + la;       // local s col
                float v = acc[i][j][r];
                if (!diag || sl < tl) m = fmaxf(m, v);
            }
#pragma unroll
            for (int off = 1; off < 16; off <<= 1) m = fmaxf(m, __shfl_xor(m, off));
            if (la == 0) atomicMax(&maxsim[b * T_ + t0 + tl], f2ord(m));
        }
    }
}

// ---- Kernel 3: gate + tanh-GELU, one float4 per thread ----
__device__ __forceinline__ float gelu_tanh(float y) {
    float t = tanhf(0.7978845608028654f * (y + 0.044715f * y * y * y));
    return 0.5f * y * (1.0f + t);
}

__global__ __launch_bounds__(256) void k_gate(const float* __restrict__ x,
                                              const float* __restrict__ log_alpha,
                                              const unsigned* __restrict__ maxsim,
                                              float* __restrict__ out) {
    int idx = blockIdx.x * 256 + threadIdx.x;     // one float4 per thread
    float la = log_alpha[0];
    float alpha = (la > 20.0f) ? la : log1pf(expf(la));
    int row = idx >> 7;                           // 128 float4-threads per row
    float m = fmaxf(ord2f(maxsim[row]), -1.0f);
    float novelty = 1.0f - (m + 1.0f) * 0.5f;
    float gate = 1.0f + alpha * novelty;
    float4 v = ((const float4*)x)[idx];
    float4 o;
    o.x = gelu_tanh(v.x * gate);
    o.y = gelu_tanh(v.y * gate);
    o.z = gelu_tanh(v.z * gate);
    o.w = gelu_tanh(v.w * gate);
    ((float4*)out)[idx] = o;
}

extern "C" void kernel_launch(void* const* d_in, const int* in_sizes, int n_in,
                              void* d_out, int out_size, void* d_ws, size_t ws_size,
                              hipStream_t stream) {
    const float* x = (const float*)d_in[0];
    const float* log_alpha = (const float*)d_in[1];
    float* out = (float*)d_out;

    unsigned* maxsim = (unsigned*)d_ws;
    unsigned char* xn = (unsigned char*)d_ws + 65536;

    const int rows = B_ * T_;                     // 16384
    k_norm<<<rows / 4, 256, 0, stream>>>(x, xn, maxsim);

    dim3 g2(NPAIR, B_);
    k_maxsim<<<g2, 256, 0, stream>>>(xn, maxsim);

    k_gate<<<(B_ * T_ * D_ / 4) / 256, 256, 0, stream>>>(x, log_alpha, maxsim, out);
}

// Round 3
// 134.560 us; speedup vs baseline: 1.6387x; 1.0412x over previous
//
#include <hip/hip_runtime.h>
#include <hip/hip_bf16.h>
#include <math.h>

// Problem shape (fixed): x [B,T,D] fp32, log_alpha scalar fp32, out [B,T,D] fp32.
#define B_ 4
#define T_ 4096
#define D_ 512
#define BT 128                 // t/s tile size per block (128x128 pair)
#define BK 64                  // K elems per pipeline step (fp8: 64 B/row)
#define STEPS (D_ / BK)        // 8
#define NT (T_ / BT)           // 32 tiles per batch
#define NPAIR (NT * (NT + 1) / 2)  // 528 lower-triangle tile pairs
#define NBLK (NPAIR * B_)      // 2112 pairs; 1056 blocks x 2 pairs each

// Workspace layout:
//   [0 .. 64KiB)                maxsim as order-preserving uint32 [B*T]
//   [64KiB .. 64KiB+B*T*D)      xn: normalized rows, fp8 e4m3, UNIT-INTERLEAVED:
//     within each 64-elem K-slab, 16B chunk C holds logical 8B units
//     {elems C*8..C*8+7} (h=0) then {elems 32+C*8..+7} (h=1). One ds_read_b128
//     serves both MFMA k-halves of a row (R2-verified zero-conflict pattern).

typedef float f32x4 __attribute__((ext_vector_type(4)));
typedef long i64x2 __attribute__((ext_vector_type(2)));

// monotone float -> uint so unsigned atomicMax orders like float
__device__ __forceinline__ unsigned f2ord(float f) {
    unsigned u = __float_as_uint(f);
    return (u & 0x80000000u) ? ~u : (u | 0x80000000u);
}
__device__ __forceinline__ float ord2f(unsigned u) {
    unsigned b = (u & 0x80000000u) ? (u ^ 0x80000000u) : ~u;
    return __uint_as_float(b);
}

__device__ __forceinline__ void async16(const unsigned char* g, unsigned char* l) {
    // 16B/lane global->LDS DMA; LDS dest = wave-uniform base + lane*16
    __builtin_amdgcn_global_load_lds(
        (const __attribute__((address_space(1))) unsigned int*)g,
        (__attribute__((address_space(3))) unsigned int*)l, 16, 0, 0);
}

// ---- Kernel 1: one wave per row. inv-norm + permuted fp8 write + init ----
__global__ __launch_bounds__(256) void k_norm(const float* __restrict__ x,
                                              unsigned char* __restrict__ xn,
                                              unsigned* __restrict__ maxsim) {
    int w = (blockIdx.x * 256 + threadIdx.x) >> 6;   // row id (B*T rows)
    int l = threadIdx.x & 63;
    const float4* xr = (const float4*)(x + (size_t)w * D_);
    float4 a = xr[l];             // elems 4l..4l+3
    float4 b = xr[l + 64];        // elems 256+4l..
    float ss = a.x * a.x + a.y * a.y + a.z * a.z + a.w * a.w +
               b.x * b.x + b.y * b.y + b.z * b.z + b.w * b.w;
#pragma unroll
    for (int off = 32; off > 0; off >>= 1) ss += __shfl_xor(ss, off);
    float inv = 1.0f / fmaxf(sqrtf(ss), 1e-12f);
    int u0 = __builtin_amdgcn_cvt_pk_fp8_f32(a.x * inv, a.y * inv, 0, false);
    u0 = __builtin_amdgcn_cvt_pk_fp8_f32(a.z * inv, a.w * inv, u0, true);
    int u1 = __builtin_amdgcn_cvt_pk_fp8_f32(b.x * inv, b.y * inv, 0, false);
    u1 = __builtin_amdgcn_cvt_pk_fp8_f32(b.z * inv, b.w * inv, u1, true);
    // permuted address (in uints) for elem group e0=4l:
    //   slab (l>>4)*16 | chunk ((l>>1)&3)*4 | half ((l>>3)&1)*2 | (l&1)
    unsigned* xo = (unsigned*)(xn + (size_t)w * D_);
    int off4 = (l >> 4) * 16 + ((l >> 1) & 3) * 4 + ((l >> 3) & 1) * 2 + (l & 1);
    xo[off4]      = (unsigned)u0;   // elems 4l..4l+3
    xo[off4 + 64] = (unsigned)u1;   // elems 256+4l.. (+4 slabs = +256 B)
    if (l == 0) maxsim[w] = f2ord(-2.0f);
}

// ---- Kernel 2: TWO (ti,si) pairs per block; fp8 MFMA; R6 3-stage pipeline ----
// Verified schedule kept bit-for-bit: 3-stage circular DMA buffer, ONE raw
// s_barrier per K-step, in-loop wait vmcnt(4), BK=64 fp8 (16 KB/stage),
// 8 ds_read_b128 + 32 MFMA per step per wave. Chunk-XOR swizzle (R2-verified
// ZERO conflicts): 16B chunk at position P of row r holds global chunk
// P ^ ((r>>1)&3); reader b128 at position qa^((la>>1)&3).
// R12 delta: pair fusion. Block handles pairs (2*bid, 2*bid+1) as ONE 16-step
// continuous pipeline (buffer modulo-3 chain and STAGE(k+2) race invariant
// unchanged across the seam); pair-1 epilogue runs inside step 8's shadow
// (register/shuffle-only) while pair-2 DMAs are in flight, then acc resets.
// Halves per-block pipeline fill + drain + epilogue-tail exposure.
// History: (256,4) spilled (R2); bf16-BK=64 killed occupancy (R3); global-
// direct frags TA-bound (R5); 1-wave blocks no TLP (R7); 256x128 tile lost
// to occupancy+tail (R8); b64 frag reads 4-way conflicted (R9); scaled
// 32x32x64 MFMA restructure latency-exposed, 3.5x regression (R10); XCD
// remap +9us regression -- xn is L2/L3-resident, no locality to win (R11).
__global__ __launch_bounds__(256) void k_maxsim(const unsigned char* __restrict__ xn,
                                                unsigned* __restrict__ maxsim) {
    __shared__ __align__(16) unsigned char Buf[3][16384];

    const int tid = threadIdx.x;
    const int wave = tid >> 6, lane = tid & 63;
    const int wm = wave >> 1, wn = wave & 1;     // 2x2 waves -> 64x64 each
    const int qa = lane >> 4, la = lane & 15;
    const int swz = (la >> 1) & 3;               // read-side row-phase XOR

    // DMA addressing: chunk index c -> row r = c>>2 (4x16B chunks = 64 B/row),
    // position c&3 holds global chunk g = (c&3) ^ ((r>>1)&3).
    const int c0 = tid,       r0_ = c0 >> 2, g0 = (c0 & 3) ^ ((r0_ >> 1) & 3);
    const int c1 = 256 + tid, r1_ = c1 >> 2, g1 = (c1 & 3) ^ ((r1_ >> 1) & 3);
    const size_t gofA0 = (size_t)r0_ * D_ + g0 * 16;
    const size_t gofA1 = (size_t)r1_ * D_ + g1 * 16;
    const int ldsb0 = (wave * 64) * 16;          // wave-uniform chunk base (bytes)
    const int ldsb1 = (256 + wave * 64) * 16;

    // decode both pairs (same batch always: NPAIR even)
    int bb[2], tt0[2], ss0[2];
    bool dg[2];
#pragma unroll
    for (int q = 0; q < 2; q++) {
        int w = blockIdx.x * 2 + q;
        int b = w / NPAIR;
        int p = w - b * NPAIR;
        int ti = (int)((sqrtf(8.0f * (float)p + 1.0f) - 1.0f) * 0.5f);
        while ((ti + 1) * (ti + 2) / 2 <= p) ti++;
        while (ti * (ti + 1) / 2 > p) ti--;
        int si = p - ti * (ti + 1) / 2;
        bb[q] = b; tt0[q] = ti * BT; ss0[q] = si * BT; dg[q] = (ti == si);
    }
    const unsigned char* pA_0 = xn + (size_t)(bb[0] * T_ + tt0[0]) * D_;
    const unsigned char* pB_0 = xn + (size_t)(bb[0] * T_ + ss0[0]) * D_;
    const unsigned char* pA_1 = xn + (size_t)(bb[1] * T_ + tt0[1]) * D_;
    const unsigned char* pB_1 = xn + (size_t)(bb[1] * T_ + ss0[1]) * D_;

    // STAGE(g): g = global step 0..15; pair = g>>3, K-step = g&7, buf = g%3.
    // g is compile-time (full unroll) so the pair select folds.
#define STAGE(g)                                                          \
    do {                                                                  \
        const unsigned char* _A = ((g) < 8) ? pA_0 : pA_1;                \
        const unsigned char* _B = ((g) < 8) ? pB_0 : pB_1;                \
        const int _o = ((g) & 7) * BK;                                    \
        async16(_A + gofA0 + _o, &Buf[(g) % 3][ldsb0]);                   \
        async16(_B + gofA0 + _o, &Buf[(g) % 3][8192 + ldsb0]);            \
        async16(_A + gofA1 + _o, &Buf[(g) % 3][ldsb1]);                   \
        async16(_B + gofA1 + _o, &Buf[(g) % 3][8192 + ldsb1]);            \
    } while (0)

    f32x4 acc[4][4];
#pragma unroll
    for (int i = 0; i < 4; i++)
#pragma unroll
        for (int j = 0; j < 4; j++) acc[i][j] = (f32x4){0.f, 0.f, 0.f, 0.f};

    // epilogue: per-row max over this tile's s-columns, then global atomicMax.
    // C/D layout (verified, dtype-independent): col = lane&15, row = (lane>>4)*4+reg
    auto epi = [&](int be, int t0e, bool diage) {
#pragma unroll
        for (int i = 0; i < 4; i++) {
#pragma unroll
            for (int r = 0; r < 4; r++) {
                int tl = wm * 64 + i * 16 + qa * 4 + r;   // local t row
                float m = -2.0f;
#pragma unroll
                for (int j = 0; j < 4; j++) {
                    int sl = wn * 64 + j * 16 + la;       // local s col
                    float v = acc[i][j][r];
                    if (!diage || sl < tl) m = fmaxf(m, v);
                }
#pragma unroll
                for (int off = 1; off < 16; off <<= 1) m = fmaxf(m, __shfl_xor(m, off));
                if (la == 0) atomicMax(&maxsim[be * T_ + t0e + tl], f2ord(m));
            }
        }
    };

    const int rpos = (qa ^ swz) * 16;            // b128 position within 64-B row

    // prologue: steps 0 and 1 in flight (4 DMA instrs each per wave)
    STAGE(0);
    STAGE(1);

#pragma unroll
    for (int k = 0; k < 16; ++k) {
        const int cur = k % 3;
        // simm16: vmcnt lo[3:0] | expcnt(7)<<4 | lgkmcnt(15)<<8
        if (k == 15) __builtin_amdgcn_s_waitcnt(0x0F70);  // vmcnt(0)
        else         __builtin_amdgcn_s_waitcnt(0x0F74);  // vmcnt(4)
        __builtin_amdgcn_s_barrier();
        __asm__ __volatile__("" ::: "memory");   // pin LDS reads below barrier
        if (k + 2 < 16) STAGE(k + 2);

        if (k == 8) {
            // pair-1 epilogue in step-8's shadow (no LDS -> no barrier needed);
            // pair-2 DMAs (stages 8..10) are already in flight.
            epi(bb[0], tt0[0], dg[0]);
#pragma unroll
            for (int i = 0; i < 4; i++)
#pragma unroll
                for (int j = 0; j < 4; j++) acc[i][j] = (f32x4){0.f, 0.f, 0.f, 0.f};
        }

        const unsigned char* As = &Buf[cur][0];
        const unsigned char* Bs = &Buf[cur][8192];
        // ONE b128 per row: [0]=h0 fragment (k 0..31), [1]=h1 (k 32..63)
        i64x2 af[4], bfr[4];
#pragma unroll
        for (int i = 0; i < 4; i++)
            af[i] = *(const i64x2*)&As[(wm * 64 + i * 16 + la) * 64 + rpos];
#pragma unroll
        for (int j = 0; j < 4; j++)
            bfr[j] = *(const i64x2*)&Bs[(wn * 64 + j * 16 + la) * 64 + rpos];
#pragma unroll
        for (int h = 0; h < 2; h++)
#pragma unroll
            for (int i = 0; i < 4; i++)
#pragma unroll
                for (int j = 0; j < 4; j++)
                    acc[i][j] = __builtin_amdgcn_mfma_f32_16x16x32_fp8_fp8(
                        af[i][h], bfr[j][h], acc[i][j], 0, 0, 0);
    }
#undef STAGE

    epi(bb[1], tt0[1], dg[1]);
}

// ---- Kernel 3: gate + tanh-GELU, one float4 per thread ----
__device__ __forceinline__ float gelu_tanh(float y) {
    float t = tanhf(0.7978845608028654f * (y + 0.044715f * y * y * y));
    return 0.5f * y * (1.0f + t);
}

__global__ __launch_bounds__(256) void k_gate(const float* __restrict__ x,
                                              const float* __restrict__ log_alpha,
                                              const unsigned* __restrict__ maxsim,
                                              float* __restrict__ out) {
    int idx = blockIdx.x * 256 + threadIdx.x;     // one float4 per thread
    float la = log_alpha[0];
    float alpha = (la > 20.0f) ? la : log1pf(expf(la));
    int row = idx >> 7;                           // 128 float4-threads per row
    float m = fmaxf(ord2f(maxsim[row]), -1.0f);
    float novelty = 1.0f - (m + 1.0f) * 0.5f;
    float gate = 1.0f + alpha * novelty;
    float4 v = ((const float4*)x)[idx];
    float4 o;
    o.x = gelu_tanh(v.x * gate);
    o.y = gelu_tanh(v.y * gate);
    o.z = gelu_tanh(v.z * gate);
    o.w = gelu_tanh(v.w * gate);
    ((float4*)out)[idx] = o;
}

extern "C" void kernel_launch(void* const* d_in, const int* in_sizes, int n_in,
                              void* d_out, int out_size, void* d_ws, size_t ws_size,
                              hipStream_t stream) {
    const float* x = (const float*)d_in[0];
    const float* log_alpha = (const float*)d_in[1];
    float* out = (float*)d_out;

    unsigned* maxsim = (unsigned*)d_ws;
    unsigned char* xn = (unsigned char*)d_ws + 65536;

    const int rows = B_ * T_;                     // 16384
    k_norm<<<rows / 4, 256, 0, stream>>>(x, xn, maxsim);

    k_maxsim<<<NBLK / 2, 256, 0, stream>>>(xn, maxsim);

    k_gate<<<(B_ * T_ * D_ / 4) / 256, 256, 0, stream>>>(x, log_alpha, maxsim, out);
}